// Round 2
// baseline (202.951 us; speedup 1.0000x reference)
//
#include <hip/hip_runtime.h>

typedef _Float16 f16;
typedef _Float16 f16x4 __attribute__((ext_vector_type(4)));
typedef _Float16 f16x8 __attribute__((ext_vector_type(8)));
typedef float f32x4 __attribute__((ext_vector_type(4)));

#define MFMA16(a, b, c) __builtin_amdgcn_mfma_f32_16x16x32_f16((a), (b), (c), 0, 0, 0)

// ---------------- prep: f32->f16 weights + 49x49 relative-bias table ----------------
__global__ void prep_kernel(const float* __restrict__ Wq, const float* __restrict__ Wo,
                            const float* __restrict__ Brel,
                            f16* __restrict__ wq16, f16* __restrict__ wo16,
                            float* __restrict__ bias49) {
  int tid = blockIdx.x * blockDim.x + threadIdx.x;
  int nthr = gridDim.x * blockDim.x;
  for (int i = tid; i < 576 * 192; i += nthr) wq16[i] = (f16)Wq[i];
  for (int i = tid; i < 192 * 192; i += nthr) wo16[i] = (f16)Wo[i];
  for (int idx = tid; idx < 49 * 49; idx += nthr) {
    int i = idx / 49, j = idx % 49;
    // Replicate numpy PyArray_Arange + DOUBLE_fill exactly:
    //   buf[0]=1; buf[1]=fl(1+step); delta=buf[1]-buf[0]; buf[t]=fl(1+fl(t*delta))
    volatile double one  = 1.0;
    volatile double step = 1.0 / 7.0;
    volatile double b1   = one + step;
    volatile double delta = b1 - one;        // (M-2)*2^-55 != fl(1/7)
    volatile double mj = (double)j * delta;
    volatile double sj = 1.0 + mj;
    volatile double mi = (double)i * delta;
    volatile double si = 1.0 + mi;
    double d = (double)sj - (double)si;
    int xd = (int)d;                      // trunc toward zero, like astype(int32)
    int yd = (j % 7) - (i % 7);
    int xm = ((xd % 13) + 13) % 13;
    int ym = ((yd % 13) + 13) % 13;
    bias49[idx] = Brel[xm * 13 + ym];
  }
}

// ---------------- fused shifted-window MSA: one block per (batch, window) ----------------
__launch_bounds__(384)
__global__ void swin_kernel(const float* __restrict__ x,
                            const float* __restrict__ bqkv,
                            const float* __restrict__ bout,
                            const f16* __restrict__ wq16,
                            const f16* __restrict__ wo16,
                            const float* __restrict__ bias49,
                            float* __restrict__ out) {
  __shared__ f16 xs[64 * 192];        // x tile (f16); reused as attention-output O[64][192]
  __shared__ f16 qkv[6][3][2048];     // per head: q[64][32], k[64][32], vT[32][64]
  __shared__ f16 plds[6][4096];       // per head: P[64][64] (unnormalized exp)
  __shared__ f16 biasl[4096];         // bias+mask table [i][j] 64x64

  const int tid = threadIdx.x;
  const int bid = blockIdx.x;
  const int b  = bid >> 6;
  const int wh = (bid >> 3) & 7;
  const int ww = bid & 7;
  const int lane = tid & 63;
  const int wv = tid >> 6;            // wave index == head
  const int lr = lane & 15;
  const int lg = lane >> 4;

  // ---- phase 0: bias/mask table + x staging (rolled -4 window gather) ----
  {
    const bool mA = (wh == 7), mB = (ww == 7);
    for (int idx = tid; idx < 64 * 64; idx += 384) {
      int i = idx >> 6, j = idx & 63;
      float v = -60000.0f;            // kills padding j>=49 and masked entries
      if (i < 49 && j < 49) {
        bool msk = false;
        if (mA) msk |= ((i / 7 >= 4) != (j / 7 >= 4));
        if (mB) msk |= ((i % 7 >= 4) != (j % 7 >= 4));
        v = msk ? -60000.0f : bias49[i * 49 + j];
      }
      biasl[idx] = (f16)v;
    }
    const float* xb = x + (size_t)b * (3136 * 192);
    for (int idx = tid; idx < 49 * 48; idx += 384) {
      int t = idx / 48, c4 = idx % 48;
      int m1 = t / 7, m2 = t % 7;
      int y  = wh * 7 + m1 + 4; if (y  >= 56) y  -= 56;
      int xx = ww * 7 + m2 + 4; if (xx >= 56) xx -= 56;
      float4 v = *(const float4*)(xb + ((y * 56 + xx) * 192 + c4 * 4));
      f16x4 h = { (f16)v.x, (f16)v.y, (f16)v.z, (f16)v.w };
      *(f16x4*)(&xs[t * 192 + c4 * 4]) = h;
    }
    for (int idx = tid; idx < 15 * 24; idx += 384) {   // zero pad rows 49..63
      int t = 49 + idx / 24, c8 = idx % 24;
      f16x8 z = {};
      *(f16x8*)(&xs[t * 192 + c8 * 8]) = z;
    }
  }
  __syncthreads();   // B1

  // ---- phase 1: QKV projection for head wv.  out[i][n], n=(wv*32+e)*3+kk ----
  {
    f32x4 acc[3][2][4];
    #pragma unroll
    for (int kk = 0; kk < 3; ++kk)
      #pragma unroll
      for (int et = 0; et < 2; ++et)
        #pragma unroll
        for (int it = 0; it < 4; ++it)
          acc[kk][et][it] = (f32x4){0.f, 0.f, 0.f, 0.f};

    #pragma unroll
    for (int ks = 0; ks < 6; ++ks) {
      f16x8 a[4];
      #pragma unroll
      for (int it = 0; it < 4; ++it)
        a[it] = *(const f16x8*)(&xs[(it * 16 + lr) * 192 + ks * 32 + lg * 8]);
      #pragma unroll
      for (int kk = 0; kk < 3; ++kk) {
        #pragma unroll
        for (int et = 0; et < 2; ++et) {
          int n = (wv * 32 + et * 16 + lr) * 3 + kk;
          f16x8 bw = *(const f16x8*)(&wq16[(size_t)n * 192 + ks * 32 + lg * 8]);
          #pragma unroll
          for (int it = 0; it < 4; ++it)
            acc[kk][et][it] = MFMA16(a[it], bw, acc[kk][et][it]);
        }
      }
    }
    const float SCALE = 0.17677669529663687f;   // 1/sqrt(32), folded into q
    #pragma unroll
    for (int kk = 0; kk < 3; ++kk) {
      #pragma unroll
      for (int et = 0; et < 2; ++et) {
        int e = et * 16 + lr;
        float bq = bqkv[(wv * 32 + e) * 3 + kk];
        #pragma unroll
        for (int it = 0; it < 4; ++it) {
          float vals[4];
          #pragma unroll
          for (int r = 0; r < 4; ++r) {
            float v = acc[kk][et][it][r] + bq;
            if (kk == 0) v *= SCALE;
            vals[r] = v;
          }
          if (kk < 2) {                 // q,k: [token][e]
            #pragma unroll
            for (int r = 0; r < 4; ++r) {
              int i = it * 16 + lg * 4 + r;
              qkv[wv][kk][i * 32 + e] = (f16)vals[r];
            }
          } else {                      // v: transposed vT[e][token]
            f16x4 pk = { (f16)vals[0], (f16)vals[1], (f16)vals[2], (f16)vals[3] };
            *(f16x4*)(&qkv[wv][2][e * 64 + it * 16 + lg * 4]) = pk;
          }
        }
      }
    }
  }
  __syncthreads();   // B2: all xs reads done -> xs reusable as O

  // ---- phase 2: attention for head wv ----
  float rinv[4];
  {
    // S^T = mfma(K, Q): C[j][i], col i = lr, row j = lg*4+r  (softmax rows are lane-local)
    f16x8 qf[4];
    #pragma unroll
    for (int itt = 0; itt < 4; ++itt)
      qf[itt] = *(const f16x8*)(&qkv[wv][0][(itt * 16 + lr) * 32 + lg * 8]);
    f32x4 sacc[4][4];
    #pragma unroll
    for (int jt = 0; jt < 4; ++jt) {
      f16x8 kf = *(const f16x8*)(&qkv[wv][1][(jt * 16 + lr) * 32 + lg * 8]);
      #pragma unroll
      for (int itt = 0; itt < 4; ++itt) {
        f32x4 z = (f32x4){0.f, 0.f, 0.f, 0.f};
        sacc[jt][itt] = MFMA16(kf, qf[itt], z);
      }
    }
    // softmax over j for each of the lane's 4 query-cols i
    #pragma unroll
    for (int itt = 0; itt < 4; ++itt) {
      int i = itt * 16 + lr;
      float sv[16];
      #pragma unroll
      for (int jt = 0; jt < 4; ++jt) {
        f16x4 bb = *(const f16x4*)(&biasl[i * 64 + jt * 16 + lg * 4]);
        #pragma unroll
        for (int r = 0; r < 4; ++r)
          sv[jt * 4 + r] = sacc[jt][itt][r] + (float)bb[r];
      }
      float mx = sv[0];
      #pragma unroll
      for (int t = 1; t < 16; ++t) mx = fmaxf(mx, sv[t]);
      mx = fmaxf(mx, __shfl_xor(mx, 16));
      mx = fmaxf(mx, __shfl_xor(mx, 32));
      float sum = 0.f;
      #pragma unroll
      for (int t = 0; t < 16; ++t) { sv[t] = __expf(sv[t] - mx); sum += sv[t]; }
      sum += __shfl_xor(sum, 16);
      sum += __shfl_xor(sum, 32);
      rinv[itt] = 1.0f / sum;
      #pragma unroll
      for (int jt = 0; jt < 4; ++jt) {
        f16x4 pk = { (f16)sv[jt*4+0], (f16)sv[jt*4+1], (f16)sv[jt*4+2], (f16)sv[jt*4+3] };
        *(f16x4*)(&plds[wv][i * 64 + jt * 16 + lg * 4]) = pk;
      }
    }
    // O^T = mfma(vT, P): C[e][i]
    f32x4 oacc[2][4];
    #pragma unroll
    for (int et = 0; et < 2; ++et)
      #pragma unroll
      for (int itt = 0; itt < 4; ++itt)
        oacc[et][itt] = (f32x4){0.f, 0.f, 0.f, 0.f};
    #pragma unroll
    for (int ksj = 0; ksj < 2; ++ksj) {
      f16x8 av[2];
      #pragma unroll
      for (int et = 0; et < 2; ++et)
        av[et] = *(const f16x8*)(&qkv[wv][2][(et * 16 + lr) * 64 + ksj * 32 + lg * 8]);
      #pragma unroll
      for (int itt = 0; itt < 4; ++itt) {
        f16x8 bp = *(const f16x8*)(&plds[wv][(itt * 16 + lr) * 64 + ksj * 32 + lg * 8]);
        #pragma unroll
        for (int et = 0; et < 2; ++et)
          oacc[et][itt] = MFMA16(av[et], bp, oacc[et][itt]);
      }
    }
    // normalize + write O into xs region: O[token i][head*32+e]
    #pragma unroll
    for (int et = 0; et < 2; ++et)
      #pragma unroll
      for (int itt = 0; itt < 4; ++itt) {
        int i = itt * 16 + lr;
        f16x4 pk;
        #pragma unroll
        for (int r = 0; r < 4; ++r) pk[r] = (f16)(oacc[et][itt][r] * rinv[itt]);
        *(f16x4*)(&xs[i * 192 + wv * 32 + et * 16 + lg * 4]) = pk;
      }
  }
  __syncthreads();   // B3: O complete

  // ---- phase 3: output projection Z = O @ Wo^T + bo, rolled (+3) scatter ----
  {
    f32x4 zacc[2][4];
    #pragma unroll
    for (int nt = 0; nt < 2; ++nt)
      #pragma unroll
      for (int it = 0; it < 4; ++it)
        zacc[nt][it] = (f32x4){0.f, 0.f, 0.f, 0.f};
    #pragma unroll
    for (int ks = 0; ks < 6; ++ks) {
      f16x8 a[4];
      #pragma unroll
      for (int it = 0; it < 4; ++it)
        a[it] = *(const f16x8*)(&xs[(it * 16 + lr) * 192 + ks * 32 + lg * 8]);
      #pragma unroll
      for (int nt = 0; nt < 2; ++nt) {
        int n = wv * 32 + nt * 16 + lr;
        f16x8 bw = *(const f16x8*)(&wo16[(size_t)n * 192 + ks * 32 + lg * 8]);
        #pragma unroll
        for (int it = 0; it < 4; ++it)
          zacc[nt][it] = MFMA16(a[it], bw, zacc[nt][it]);
      }
    }
    float* outb = out + (size_t)b * (3136 * 192);
    #pragma unroll
    for (int nt = 0; nt < 2; ++nt) {
      int n = wv * 32 + nt * 16 + lr;
      float bo = bout[n];
      #pragma unroll
      for (int it = 0; it < 4; ++it) {
        #pragma unroll
        for (int r = 0; r < 4; ++r) {
          int i = it * 16 + lg * 4 + r;
          if (i < 49) {
            int m1 = i / 7, m2 = i % 7;
            int y  = wh * 7 + m1 + 3; if (y  >= 56) y  -= 56;
            int xx = ww * 7 + m2 + 3; if (xx >= 56) xx -= 56;
            outb[(size_t)(y * 56 + xx) * 192 + n] = zacc[nt][it][r] + bo;
          }
        }
      }
    }
  }
}

extern "C" void kernel_launch(void* const* d_in, const int* in_sizes, int n_in,
                              void* d_out, int out_size, void* d_ws, size_t ws_size,
                              hipStream_t stream) {
  const float* x    = (const float*)d_in[0];
  const float* Wq   = (const float*)d_in[1];
  const float* bq   = (const float*)d_in[2];
  const float* Wo   = (const float*)d_in[3];
  const float* bo   = (const float*)d_in[4];
  const float* Brel = (const float*)d_in[5];

  f16*   wq16   = (f16*)d_ws;                         // 576*192*2   = 221184 B
  f16*   wo16   = (f16*)((char*)d_ws + 0x40000);      // 192*192*2   =  73728 B
  float* bias49 = (float*)((char*)d_ws + 0x60000);    // 49*49*4     =   9604 B

  hipLaunchKernelGGL(prep_kernel, dim3(256), dim3(256), 0, stream,
                     Wq, Wo, Brel, wq16, wo16, bias49);
  hipLaunchKernelGGL(swin_kernel, dim3(32 * 8 * 8), dim3(384), 0, stream,
                     x, bq, bo, wq16, wo16, bias49, (float*)d_out);
}